// Round 3
// baseline (124.957 us; speedup 1.0000x reference)
//
#include <hip/hip_runtime.h>

// DCN CrossLayer: B=16384, F=1024, L=3, fp32.
// Closed form of the 3-layer recurrence (see R1):
//   d_j = x0.w_j ; t01=b0.w1 ; t02=b0.w2 ; t12=b1.w2
//   s0=d0 ; s1=(1+s0)d1+t01 ; s2=(1+s0+s1)d2+t02+t12
//   out = x0*(1+s0+s1+s2) + (b0+b1+b2)
//
// R2 changes:
//  - 2 rows per wave: 2x memory in flight per wave; t01/t02/t12 are
//    row-independent and shared, so 9 butterfly values serve 2 rows.
//  - Nontemporal loads for x and nontemporal stores for out: both are
//    pure streams (zero reuse) — keep them out of L2 so the 12 KB w/b
//    working set and the read stream don't fight write-allocate traffic.
// Memory floor: 64 MiB read + 64 MiB write ≈ 21 us at 6.3 TB/s.

constexpr int B = 16384;
constexpr int F = 1024;
constexpr int ROWS_PER_WAVE = 2;
constexpr int WAVES_PER_BLOCK = 4;
constexpr int BLOCK = 64 * WAVES_PER_BLOCK;
constexpr int ROWS_PER_BLOCK = ROWS_PER_WAVE * WAVES_PER_BLOCK;  // 8

typedef float v4f __attribute__((ext_vector_type(4)));

__global__ __launch_bounds__(BLOCK) void cross_layer_kernel(
    const float* __restrict__ x,        // [B, F]
    const float* __restrict__ kernels,  // [3, F]
    const float* __restrict__ bias,     // [3, F]
    float* __restrict__ out)            // [B, F]
{
    const int lane = threadIdx.x & 63;
    const int wave = threadIdx.x >> 6;
    const int row0 = (blockIdx.x * WAVES_PER_BLOCK + wave) * ROWS_PER_WAVE;

    const v4f* xa = (const v4f*)(x + (size_t)row0 * F);
    const v4f* xb = (const v4f*)(x + (size_t)(row0 + 1) * F);
    const v4f* w0v = (const v4f*)(kernels);
    const v4f* w1v = (const v4f*)(kernels + F);
    const v4f* w2v = (const v4f*)(kernels + 2 * F);
    const v4f* b0v = (const v4f*)(bias);
    const v4f* b1v = (const v4f*)(bias + F);
    const v4f* b2v = (const v4f*)(bias + 2 * F);

    // Front-load both x rows (nontemporal: read-once stream, skip L2).
    v4f xA[4], xB[4];
#pragma unroll
    for (int c = 0; c < 4; ++c) {
        xA[c] = __builtin_nontemporal_load(&xa[c * 64 + lane]);
        xB[c] = __builtin_nontemporal_load(&xb[c * 64 + lane]);
    }

    // Partials: per-row dots dA0..dA2, dB0..dB2 + shared t01,t02,t12.
    float dA0 = 0.f, dA1 = 0.f, dA2 = 0.f;
    float dB0 = 0.f, dB1 = 0.f, dB2 = 0.f;
    float t01 = 0.f, t02 = 0.f, t12 = 0.f;

#pragma unroll
    for (int c = 0; c < 4; ++c) {
        const int i = c * 64 + lane;
        const v4f w0 = w0v[i];
        const v4f w1 = w1v[i];
        const v4f w2 = w2v[i];
        const v4f b0 = b0v[i];
        const v4f b1 = b1v[i];

#pragma unroll
        for (int e = 0; e < 4; ++e) {
            dA0 = fmaf(xA[c][e], w0[e], dA0);
            dA1 = fmaf(xA[c][e], w1[e], dA1);
            dA2 = fmaf(xA[c][e], w2[e], dA2);
            dB0 = fmaf(xB[c][e], w0[e], dB0);
            dB1 = fmaf(xB[c][e], w1[e], dB1);
            dB2 = fmaf(xB[c][e], w2[e], dB2);
            t01 = fmaf(b0[e], w1[e], t01);
            t02 = fmaf(b0[e], w2[e], t02);
            t12 = fmaf(b1[e], w2[e], t12);
        }
    }

    // One interleaved 9-value butterfly over 64 lanes.
#pragma unroll
    for (int off = 32; off >= 1; off >>= 1) {
        dA0 += __shfl_xor(dA0, off, 64);
        dA1 += __shfl_xor(dA1, off, 64);
        dA2 += __shfl_xor(dA2, off, 64);
        dB0 += __shfl_xor(dB0, off, 64);
        dB1 += __shfl_xor(dB1, off, 64);
        dB2 += __shfl_xor(dB2, off, 64);
        t01 += __shfl_xor(t01, off, 64);
        t02 += __shfl_xor(t02, off, 64);
        t12 += __shfl_xor(t12, off, 64);
    }

    // Scalar recurrence per row.
    const float tc = t02 + t12;
    const float a1A = 1.f + dA0;
    const float s1A = fmaf(a1A, dA1, t01);
    const float a2A = a1A + s1A;
    const float s2A = fmaf(a2A, dA2, tc);
    const float SA  = a2A + s2A;

    const float a1B = 1.f + dB0;
    const float s1B = fmaf(a1B, dB1, t01);
    const float a2B = a1B + s1B;
    const float s2B = fmaf(a2B, dB2, tc);
    const float SB  = a2B + s2B;

    // Epilogue: out = x0*S + (b0+b1+b2); b re-read from L1 (12 KB resident),
    // stores nontemporal (write-once stream).
    v4f* oa = (v4f*)(out + (size_t)row0 * F);
    v4f* ob = (v4f*)(out + (size_t)(row0 + 1) * F);
#pragma unroll
    for (int c = 0; c < 4; ++c) {
        const int i = c * 64 + lane;
        const v4f b0 = b0v[i];
        const v4f b1 = b1v[i];
        const v4f b2 = b2v[i];
        v4f bs;
#pragma unroll
        for (int e = 0; e < 4; ++e) bs[e] = b0[e] + b1[e] + b2[e];
        v4f oA, oB;
#pragma unroll
        for (int e = 0; e < 4; ++e) {
            oA[e] = fmaf(xA[c][e], SA, bs[e]);
            oB[e] = fmaf(xB[c][e], SB, bs[e]);
        }
        __builtin_nontemporal_store(oA, &oa[i]);
        __builtin_nontemporal_store(oB, &ob[i]);
    }
}

extern "C" void kernel_launch(void* const* d_in, const int* in_sizes, int n_in,
                              void* d_out, int out_size, void* d_ws, size_t ws_size,
                              hipStream_t stream) {
    const float* x       = (const float*)d_in[0];
    const float* kernels = (const float*)d_in[1];
    const float* bias    = (const float*)d_in[2];
    float* out           = (float*)d_out;

    dim3 grid(B / ROWS_PER_BLOCK);  // 2048 blocks
    dim3 block(BLOCK);              // 256 threads = 4 waves
    cross_layer_kernel<<<grid, block, 0, stream>>>(x, kernels, bias, out);
}

// Round 4
// 123.324 us; speedup vs baseline: 1.0132x; 1.0132x over previous
//
#include <hip/hip_runtime.h>

// DCN CrossLayer: B=16384, F=1024, L=3, fp32.
// Closed form of the 3-layer recurrence:
//   d_j = x0.w_j ; t01=b0.w1 ; t02=b0.w2 ; t12=b1.w2
//   s0=d0 ; s1=(1+s0)d1+t01 ; s2=(1+s0+s1)d2+t02+t12
//   out = x0*(1+s0+s1+s2) + (b0+b1+b2)
//
// Best-measured config (R2: 119.9 us total, kernel <40 us, invisible behind
// the harness's ~41 us 256 MiB re-poison fills): one wave per row, 6-value
// interleaved butterfly, plain (cached) loads/stores. R3's 2-rows/wave +
// nontemporal variant measured 125.0 -> reverted. Mandatory HBM traffic:
// 64 MiB read + 64 MiB write ~= 20 us at the 6.6 TB/s the fills achieve.

constexpr int B = 16384;
constexpr int F = 1024;
constexpr int ROWS_PER_BLOCK = 4;   // 4 waves/block, 1 row/wave
constexpr int BLOCK = 64 * ROWS_PER_BLOCK;

__global__ __launch_bounds__(BLOCK) void cross_layer_kernel(
    const float* __restrict__ x,        // [B, F]
    const float* __restrict__ kernels,  // [3, F]
    const float* __restrict__ bias,     // [3, F]
    float* __restrict__ out)            // [B, F]
{
    const int lane = threadIdx.x & 63;
    const int wave = threadIdx.x >> 6;
    const int row  = blockIdx.x * ROWS_PER_BLOCK + wave;

    const float4* xrow = (const float4*)(x + (size_t)row * F);
    const float4* w0v  = (const float4*)(kernels);
    const float4* w1v  = (const float4*)(kernels + F);
    const float4* w2v  = (const float4*)(kernels + 2 * F);
    const float4* b0v  = (const float4*)(bias);
    const float4* b1v  = (const float4*)(bias + F);
    const float4* b2v  = (const float4*)(bias + 2 * F);

    // Front-load the x row (coalesced 16B/lane).
    float4 x0[4];
#pragma unroll
    for (int c = 0; c < 4; ++c) x0[c] = xrow[c * 64 + lane];

    // 6 independent partial sums: d0,d1,d2, t01,t02,t12
    float p0 = 0.f, p1 = 0.f, p2 = 0.f, p3 = 0.f, p4 = 0.f, p5 = 0.f;
#pragma unroll
    for (int c = 0; c < 4; ++c) {
        const int i = c * 64 + lane;
        const float4 w0 = w0v[i];
        const float4 w1 = w1v[i];
        const float4 w2 = w2v[i];
        const float4 b0 = b0v[i];
        const float4 b1 = b1v[i];

        p0 = fmaf(x0[c].x, w0.x, p0); p0 = fmaf(x0[c].y, w0.y, p0);
        p0 = fmaf(x0[c].z, w0.z, p0); p0 = fmaf(x0[c].w, w0.w, p0);

        p1 = fmaf(x0[c].x, w1.x, p1); p1 = fmaf(x0[c].y, w1.y, p1);
        p1 = fmaf(x0[c].z, w1.z, p1); p1 = fmaf(x0[c].w, w1.w, p1);

        p2 = fmaf(x0[c].x, w2.x, p2); p2 = fmaf(x0[c].y, w2.y, p2);
        p2 = fmaf(x0[c].z, w2.z, p2); p2 = fmaf(x0[c].w, w2.w, p2);

        p3 = fmaf(b0.x, w1.x, p3); p3 = fmaf(b0.y, w1.y, p3);
        p3 = fmaf(b0.z, w1.z, p3); p3 = fmaf(b0.w, w1.w, p3);

        p4 = fmaf(b0.x, w2.x, p4); p4 = fmaf(b0.y, w2.y, p4);
        p4 = fmaf(b0.z, w2.z, p4); p4 = fmaf(b0.w, w2.w, p4);

        p5 = fmaf(b1.x, w2.x, p5); p5 = fmaf(b1.y, w2.y, p5);
        p5 = fmaf(b1.z, w2.z, p5); p5 = fmaf(b1.w, w2.w, p5);
    }

    // Single interleaved 6-value butterfly over 64 lanes.
#pragma unroll
    for (int off = 32; off >= 1; off >>= 1) {
        p0 += __shfl_xor(p0, off, 64);
        p1 += __shfl_xor(p1, off, 64);
        p2 += __shfl_xor(p2, off, 64);
        p3 += __shfl_xor(p3, off, 64);
        p4 += __shfl_xor(p4, off, 64);
        p5 += __shfl_xor(p5, off, 64);
    }

    // Scalar recurrence (all lanes hold the full sums).
    const float a1 = 1.f + p0;                 // 1 + s0
    const float s1 = fmaf(a1, p1, p3);         // (1+s0)*d1 + b0.w1
    const float a2 = a1 + s1;                  // 1 + s0 + s1
    const float s2 = fmaf(a2, p2, p4 + p5);    // (1+s0+s1)*d2 + (b0+b1).w2
    const float S  = a2 + s2;                  // 1 + s0 + s1 + s2

    // Epilogue: out = x0*S + (b0+b1+b2). b re-read (L1/L2-resident, 12 KB).
    float4* orow = (float4*)(out + (size_t)row * F);
#pragma unroll
    for (int c = 0; c < 4; ++c) {
        const int i = c * 64 + lane;
        const float4 b0 = b0v[i];
        const float4 b1 = b1v[i];
        const float4 b2 = b2v[i];
        float4 o;
        o.x = fmaf(x0[c].x, S, b0.x + b1.x + b2.x);
        o.y = fmaf(x0[c].y, S, b0.y + b1.y + b2.y);
        o.z = fmaf(x0[c].z, S, b0.z + b1.z + b2.z);
        o.w = fmaf(x0[c].w, S, b0.w + b1.w + b2.w);
        orow[i] = o;
    }
}

extern "C" void kernel_launch(void* const* d_in, const int* in_sizes, int n_in,
                              void* d_out, int out_size, void* d_ws, size_t ws_size,
                              hipStream_t stream) {
    const float* x       = (const float*)d_in[0];
    const float* kernels = (const float*)d_in[1];
    const float* bias    = (const float*)d_in[2];
    float* out           = (float*)d_out;

    dim3 grid(B / ROWS_PER_BLOCK);  // 4096 blocks
    dim3 block(BLOCK);              // 256 threads = 4 waves
    cross_layer_kernel<<<grid, block, 0, stream>>>(x, kernels, bias, out);
}